// Round 8
// baseline (110.613 us; speedup 1.0000x reference)
//
#include <hip/hip_runtime.h>

typedef float v2f __attribute__((ext_vector_type(2)));

#define NEG_INF (-__builtin_huge_valf())

#define CCH   4                 // c's per LDS chunk
#define HB    4                 // output h rows per wave tile
#define ROWS  (HB + 2)          // 6 (h halo)
#define XSTR  64                // xs row stride: pure float4 data, b128-balanced
#define SLOTS 6                 // CCH*ROWS*16 float4 / 64 threads

// DPP row-shifts (16-lane rows == one hr group). bound_ctrl=0 keeps `old`
// for invalid source lanes: passing old=-inf gives the w-halo for free
// (wg==0 left edge, wg==15 right edge) — no cndmask, no LDS edge array.
__device__ __forceinline__ float dpp_shr1(float v, float old) {   // lane wg <- wg-1
    return __int_as_float(__builtin_amdgcn_update_dpp(
        __float_as_int(old), __float_as_int(v), 0x111, 0xF, 0xF, false));
}
__device__ __forceinline__ float dpp_shl1(float v, float old) {   // lane wg <- wg+1
    return __int_as_float(__builtin_amdgcn_update_dpp(
        __float_as_int(old), __float_as_int(v), 0x101, 0xF, 0xF, false));
}

// Wave-per-tile (64 threads), 2o x 1h x 4w = 8 acc/thread.
// Grid (16,8,32) = 4096 waves -> 4 waves/SIMD. LDS 6144 B/block.
// LDS traffic is now ONLY aligned b128 (3 reads/cl, 6 writes/chunk);
// w-edges come from DPP (VALU pipe), taps from s_load (SMEM pipe).
// Adds packed as v_pk_add_f32 via float2 ext-vectors: quad gives pairs
// (m.x,m.y),(m.z,m.w) free; (le,m.x),(m.y,m.z),(m.w,re) constructed once
// per row and shared by both o's.
__global__ __launch_bounds__(64, 4)
void maxplus_conv2d_kernel(const float* __restrict__ x,
                           const float* __restrict__ kern,
                           float* __restrict__ out) {
    __shared__ float xs[CCH * ROWS * XSTR];

    const int tid = threadIdx.x;        // 0..63
    const int wg  = tid & 15;
    const int hr  = tid >> 4;           // 0..3
    const int w0  = wg << 2;

    const int h_base = blockIdx.x * HB;
    const int b      = blockIdx.y;
    const int o_base = blockIdx.z << 1; // o pair

    // ---- staging slots (chunk-invariant; computed once) ----
    const float* xb = x + (size_t)b * 64 * 64 * 64;
    const float* gsrc[SLOTS];
    float*       xdst[SLOTS];
    bool         vmask[SLOTS];
#pragma unroll
    for (int k = 0; k < SLOTS; ++k) {
        int rowid = k * 4 + hr;           // 0..23, each exactly once per wave
        int cl    = rowid / ROWS;
        int r     = rowid - cl * ROWS;
        int gh    = h_base + r - 1;       // -1..64
        bool valid = (unsigned)gh < 64u;
        int  ghc   = valid ? gh : 0;      // clamped (no OOB); value replaced by -inf
        gsrc[k]  = xb + ((size_t)cl * 64 + ghc) * 64 + wg * 4;
        xdst[k]  = &xs[rowid * XSTR + wg * 4];   // aligned ds_write_b128
        vmask[k] = valid;
    }

    const float ninf = NEG_INF;

    float acc[2][4];
#pragma unroll
    for (int oo = 0; oo < 2; ++oo)
#pragma unroll
        for (int wi = 0; wi < 4; ++wi)
            acc[oo][wi] = NEG_INF;

    // prefetch chunk 0
    float4 R[SLOTS];
#pragma unroll
    for (int k = 0; k < SLOTS; ++k) R[k] = *(const float4*)gsrc[k];

#pragma unroll 1
    for (int cc = 0; cc < 64; cc += CCH) {
        __syncthreads();   // WAR fence: prev chunk's reads before these writes

#pragma unroll
        for (int k = 0; k < SLOTS; ++k) {
            float4 v = R[k];
            if (!vmask[k]) v = make_float4(NEG_INF, NEG_INF, NEG_INF, NEG_INF);
            *(float4*)xdst[k] = v;        // cols w0..w0+3
        }

        __syncthreads();   // RAW fence: writes visible before cross-lane reads

        if (cc + CCH < 64) {   // prefetch next chunk; vmcnt rides under compute
#pragma unroll
            for (int k = 0; k < SLOTS; ++k) {
                gsrc[k] += CCH * 64 * 64;
                R[k] = *(const float4*)gsrc[k];
            }
        }

        // batch tap loads for the whole chunk (wave-uniform -> grouped s_loads)
        float kv[CCH][2][9];
#pragma unroll
        for (int cl = 0; cl < CCH; ++cl)
#pragma unroll
            for (int oo = 0; oo < 2; ++oo) {
                const float* kp = kern + ((size_t)(o_base + oo) * 64 + (cc + cl)) * 9;
#pragma unroll
                for (int t = 0; t < 9; ++t) kv[cl][oo][t] = kp[t];
            }

#pragma unroll
        for (int cl = 0; cl < CCH; ++cl) {
#pragma unroll
            for (int r = 0; r < 3; ++r) {
                const int rowid = cl * ROWS + hr + r;
                float4 m = *(const float4*)(&xs[rowid * XSTR + w0]);
                float le = dpp_shr1(m.w, ninf);   // col w0-1 (wg==0 -> -inf)
                float re = dpp_shl1(m.x, ninf);   // col w0+4 (wg==15 -> -inf)

                // window pairs (window idx 0..5 = [le, m.x..m.w, re])
                v2f P0 = {le,  m.x};   // idx (0,1)
                v2f P1 = {m.y, m.z};   // idx (2,3)
                v2f P2 = {m.w, re };   // idx (4,5)
                v2f Q0 = {m.x, m.y};   // idx (1,2)  (free: quad pair)
                v2f Q1 = {m.z, m.w};   // idx (3,4)  (free: quad pair)

#pragma unroll
                for (int oo = 0; oo < 2; ++oo) {
                    const float* k9 = kv[cl][oo];
                    v2f ka = {k9[3*r+0], k9[3*r+0]};
                    v2f kb = {k9[3*r+1], k9[3*r+1]};
                    v2f kc = {k9[3*r+2], k9[3*r+2]};
                    // v_pk_add_f32: t[kj][wi], wi pairs (0,1) and (2,3)
                    v2f a0 = P0 + ka, b0 = P1 + ka;   // kj=0
                    v2f a1 = Q0 + kb, b1 = Q1 + kb;   // kj=1
                    v2f a2 = P1 + kc, b2 = P2 + kc;   // kj=2

                    // per wi: m = fmax(m, max3(t0,t1,t2)) -> 2 VALU each
                    acc[oo][0] = fmaxf(acc[oo][0], fmaxf(fmaxf(a0.x, a1.x), a2.x));
                    acc[oo][1] = fmaxf(acc[oo][1], fmaxf(fmaxf(a0.y, a1.y), a2.y));
                    acc[oo][2] = fmaxf(acc[oo][2], fmaxf(fmaxf(b0.x, b1.x), b2.x));
                    acc[oo][3] = fmaxf(acc[oo][3], fmaxf(fmaxf(b0.y, b1.y), b2.y));
                }
            }
        }
    }

    const int h = h_base + hr;
#pragma unroll
    for (int oo = 0; oo < 2; ++oo) {
        float4 v = make_float4(acc[oo][0], acc[oo][1], acc[oo][2], acc[oo][3]);
        *(float4*)(out + ((((size_t)b * 64 + (o_base + oo)) * 64 + h) * 64 + w0)) = v;
    }
}

extern "C" void kernel_launch(void* const* d_in, const int* in_sizes, int n_in,
                              void* d_out, int out_size, void* d_ws, size_t ws_size,
                              hipStream_t stream) {
    const float* x    = (const float*)d_in[0];   // [8,64,64,64]
    const float* kern = (const float*)d_in[1];   // [64,64,3,3]
    float* out = (float*)d_out;                  // [8,64,64,64]

    dim3 grid(16, 8, 32);   // h-tiles, b, o-pairs
    dim3 block(64);
    maxplus_conv2d_kernel<<<grid, block, 0, stream>>>(x, kern, out);
}